// Round 6
// baseline (551.576 us; speedup 1.0000x reference)
//
#include <hip/hip_runtime.h>
#include <hip/hip_bf16.h>
#include <cstdint>
#include <cstddef>

constexpr int C_  = 256;
constexpr int H_  = 224;
constexpr int W_  = 224;
constexpr int P_  = 49;
constexpr int M_  = 1024;
constexpr int HW_ = H_ * W_;

constexpr size_t IMG_ELEMS = (size_t)4 * C_ * H_ * W_;
constexpr size_t SCO_ELEMS = (size_t)4 * M_ * P_ * P_;
constexpr size_t OFF_SC  = IMG_ELEMS;
constexpr size_t OFF_COV = OFF_SC  + SCO_ELEMS;
constexpr size_t OFF_L   = OFF_COV + SCO_ELEMS;
constexpr size_t OFF_EC  = OFF_L   + SCO_ELEMS;

typedef __attribute__((ext_vector_type(8))) short short8;
typedef __attribute__((ext_vector_type(4))) float f32x4;

// 4 patches per workgroup (mw quad), 1024 threads = 16 waves (4/patch).
// LDS byte map (153,600 <= 160 KiB, 1 wg/CU):
//   sA (pid)  : pid*25088            49 rows x 512B bf16, row-XOR-swizzled
//   Gb (pid)  : 100352 + pid*6272    49 rows x 128B bf16 (G-u); Lb overlay
//   Scb(pid)  : 125440 + pid*6272    49 rows x 128B bf16 Sc
//   u  (pid)  : 150528 + pid*256     64 f32
//   w  (pid)  : 151552 + pid*256     64 f32
//   T2 (pid)  : 152576 + pid*256     64 f32
// No fp32 G scratch: G lives in accumulators; softmax fully in-register
// (shfl over 16-lane q-groups); fp32 Sc carried in regs to the L epilogue
// (G-MFMA and cov-MFMA share the lane<->(p,q) map).
// Overflow-read audit (fragment rows 49..63): all overflow addresses stay
// inside the 153,600B block; regions are finite bf16/f32 by use time, or
// feed only discarded D rows/cols (G phase) / Lb's zero k-columns (Ec).
constexpr int SMEM_BYTES = 153600;

__device__ __forceinline__ int srowswz(int r) { return ((r ^ (r >> 3)) & 7) << 4; }

__global__ __launch_bounds__(1024, 1)
void psa_kernel(const float* __restrict__ x, const float* __restrict__ betap,
                float* __restrict__ out_img, float* __restrict__ out_sc,
                float* __restrict__ out_cov, float* __restrict__ out_l,
                float* __restrict__ out_ec)
{
    __shared__ __align__(16) unsigned char smem[SMEM_BYTES];

    const int tid  = threadIdx.x;
    const int bid  = blockIdx.x;
    const int qd   = ((bid & 7) << 7) | (bid >> 3);   // XCD-bijective (1024 wgs)
    const int b    = qd >> 8;
    const int qq   = qd & 255;
    const int mh   = qq >> 3;
    const int mw0  = (qq & 7) << 2;
    const int pid  = tid >> 8;          // patch within quad
    const int ptid = tid & 255;         // thread within patch
    const int ww   = (tid >> 6) & 3;    // wave within patch
    const int lane = tid & 63, l15 = lane & 15, lh = lane >> 4;
    const int mw   = mw0 + pid;
    const int bm   = (b << 10) + (mh << 5) + mw;
    const float beta = betap[0];
    const size_t xpatch = (((size_t)b * C_ * H_) + (size_t)mh * 7) * W_ + (size_t)mw * 7;

    unsigned char* sAb = smem + pid * 25088;
    unsigned char* gbB = smem + 100352 + pid * 6272;
    unsigned char* scB = smem + 125440 + pid * 6272;
    float* uArr  = (float*)(smem + 150528 + pid * 256);
    float* wArr  = (float*)(smem + 151552 + pid * 256);
    float* t2Arr = (float*)(smem + 152576 + pid * 256);

    // ---- Phase 0: stage x -> sA (bf16, swizzled). ptid = channel ----
    {
        const int c = ptid;
        const float* src = x + xpatch + (size_t)c * HW_;
        #pragma unroll
        for (int i = 0; i < 7; ++i) {
            #pragma unroll
            for (int j = 0; j < 7; ++j) {
                const int p = i * 7 + j;
                *(__hip_bfloat16*)(sAb + p * 512 + ((2 * c) ^ srowswz(p))) =
                    __float2bfloat16(src[i * W_ + j]);
            }
        }
    }
    __syncthreads();

    // ---- Phase 1: G = A A^T (MFMA, K=256). G stays in registers ----
    f32x4 gacc[4] = {f32x4{0,0,0,0}, f32x4{0,0,0,0}, f32x4{0,0,0,0}, f32x4{0,0,0,0}};
    {
        const int arow = 16 * ww + l15;
        #pragma unroll
        for (int kc = 0; kc < 8; ++kc) {
            const int cb = 64 * kc + 16 * lh;
            const short8 af = *(const short8*)(sAb + arow * 512 + (cb ^ srowswz(arow)));
            #pragma unroll
            for (int t = 0; t < 4; ++t) {
                const int brow = 16 * t + l15;
                const short8 bf = *(const short8*)(sAb + brow * 512 + (cb ^ srowswz(brow)));
                gacc[t] = __builtin_amdgcn_mfma_f32_16x16x32_bf16(af, bf, gacc[t], 0, 0, 0);
            }
        }
    }

    // ---- Phase 2: in-register row stats. Lane holds G[p][q], p=16ww+4lh+r,
    // q=16t+l15. Reduce over q via in-reg t-fold + shfl over l15 group. ----
    float mx[4];
    {
        #pragma unroll
        for (int r = 0; r < 4; ++r) {
            const int p = 16 * ww + 4 * lh + r;
            float m_ = fmaxf(fmaxf(gacc[0][r], gacc[1][r]), gacc[2][r]);
            m_ = fmaxf(m_, (l15 == 0) ? gacc[3][r] : -3.4e38f);
            float s_ = gacc[0][r] + gacc[1][r] + gacc[2][r] + ((l15 == 0) ? gacc[3][r] : 0.f);
            #pragma unroll
            for (int d = 1; d < 16; d <<= 1) {
                m_ = fmaxf(m_, __shfl_xor(m_, d));
                s_ += __shfl_xor(s_, d);
            }
            mx[r] = m_;
            if (l15 == 0 && p <= 48) uArr[p] = s_ * (1.f / 49.f);   // u = rowmean (G sym)
        }
    }
    __syncthreads();

    // ---- Phase 3: Gb = bf16(G-u); in-reg exp/rowsum/scale; Scb + Sc global ----
    float sc[4][4];   // fp32 Sc carried to L epilogue
    {
        float* sc_g = out_sc + (size_t)bm * (P_ * P_);
        #pragma unroll
        for (int r = 0; r < 4; ++r) {
            const int p = 16 * ww + 4 * lh + r;
            // Gb write (rows <= 48 only; cols 49..63 zeroed)
            if (p <= 48) {
                #pragma unroll
                for (int t = 0; t < 4; ++t) {
                    const int qv = 16 * t + l15;
                    const float gv = (qv <= 48) ? (gacc[t][r] - uArr[qv]) : 0.f;
                    *(__hip_bfloat16*)(gbB + p * 128 + ((2 * qv) ^ srowswz(p))) =
                        __float2bfloat16(gv);
                }
            }
            // exp + rowsum (masked)
            float e[4];
            #pragma unroll
            for (int t = 0; t < 4; ++t) {
                const int qv = 16 * t + l15;
                e[t] = (qv <= 48) ? __expf(gacc[t][r] - mx[r]) : 0.f;
            }
            float s_ = e[0] + e[1] + e[2] + e[3];
            #pragma unroll
            for (int d = 1; d < 16; d <<= 1) s_ += __shfl_xor(s_, d);
            const float rinv = 1.f / s_;
            #pragma unroll
            for (int t = 0; t < 4; ++t) sc[t][r] = e[t] * rinv;
            if (p <= 48) {
                #pragma unroll
                for (int t = 0; t < 4; ++t) {
                    const int qv = 16 * t + l15;
                    *(__hip_bfloat16*)(scB + p * 128 + ((2 * qv) ^ srowswz(p))) =
                        __float2bfloat16(sc[t][r]);        // q>48 stores 0
                    if (qv <= 48) sc_g[p * 49 + qv] = sc[t][r];
                }
            }
        }
    }
    __syncthreads();

    // ---- Phase 4: w = colmean(Sc) from Scb (bf16). 196 threads/patch ----
    if (ptid < 196) {
        const int r0 = ptid >> 2, s = ptid & 3;
        const int pa = s * 13, pb = (pa + 13 < 49) ? pa + 13 : 49;
        float sm = 0.f;
        for (int p = pa; p < pb; ++p)
            sm += __bfloat162float(
                *(const __hip_bfloat16*)(scB + p * 128 + ((2 * r0) ^ srowswz(p))));
        sm += __shfl_xor(sm, 1);
        sm += __shfl_xor(sm, 2);
        if (s == 0) wArr[r0] = sm * (1.f / 49.f);
    }
    __syncthreads();

    // ---- Phase 5: T2[p] = sum_r Gb[p][r] * w[r] ----
    if (ptid < 196) {
        const int p0 = ptid >> 2, s = ptid & 3;
        const int ra = s * 13, rb = (ra + 13 < 49) ? ra + 13 : 49;
        float sm = 0.f;
        for (int r = ra; r < rb; ++r) {
            const float gb = __bfloat162float(
                *(const __hip_bfloat16*)(gbB + p0 * 128 + ((2 * r) ^ srowswz(p0))));
            sm += gb * wArr[r];
        }
        sm += __shfl_xor(sm, 1);
        sm += __shfl_xor(sm, 2);
        if (s == 0) t2Arr[p0] = sm;
    }
    __syncthreads();

    // ---- Phase 6: cov MFMA: D = Gb . Scb^T (K=64) ----
    f32x4 cacc[4] = {f32x4{0,0,0,0}, f32x4{0,0,0,0}, f32x4{0,0,0,0}, f32x4{0,0,0,0}};
    {
        const int arow = 16 * ww + l15;
        #pragma unroll
        for (int kc = 0; kc < 2; ++kc) {
            const int cb = 64 * kc + 16 * lh;
            const short8 af = *(const short8*)(gbB + arow * 128 + (cb ^ srowswz(arow)));
            #pragma unroll
            for (int t = 0; t < 4; ++t) {
                const int brow = 16 * t + l15;
                const short8 bf = *(const short8*)(scB + brow * 128 + (cb ^ srowswz(brow)));
                cacc[t] = __builtin_amdgcn_mfma_f32_16x16x32_bf16(af, bf, cacc[t], 0, 0, 0);
            }
        }
    }
    __syncthreads();   // cov reads done before Lb overlays Gb

    // ---- Phase 7: cv = (cacc - T2[p])/49; L = Sc + cv; write cov/L/Lb ----
    {
        float* cov_g = out_cov + (size_t)bm * (P_ * P_);
        float* l_g   = out_l   + (size_t)bm * (P_ * P_);
        #pragma unroll
        for (int t = 0; t < 4; ++t) {
            const int qv = 16 * t + l15;
            #pragma unroll
            for (int r = 0; r < 4; ++r) {
                const int p = 16 * ww + 4 * lh + r;
                if (p <= 48 && qv <= 48) {
                    const float cv = (cacc[t][r] - t2Arr[p]) * (1.f / 49.f);
                    const float lv = sc[t][r] + cv;
                    cov_g[p * 49 + qv] = cv;
                    l_g  [p * 49 + qv] = lv;
                    *(__hip_bfloat16*)(gbB + p * 128 + ((2 * qv) ^ srowswz(p))) =
                        __float2bfloat16(lv);   // Lb; cols 49..63 keep zeros
                }
            }
        }
    }
    __syncthreads();

    // ---- Phase 8: Ec^T = A^T . L^T (D[c][p]); wave ww -> c in [64ww, +64) ----
    {
        f32x4 eacc[4][4];   // [ct][pt]
        #pragma unroll
        for (int i = 0; i < 4; ++i)
            #pragma unroll
            for (int j2 = 0; j2 < 4; ++j2) eacc[i][j2] = f32x4{0, 0, 0, 0};

        #pragma unroll
        for (int kc = 0; kc < 2; ++kc) {
            const int cb = 64 * kc + 16 * lh;
            short8 bf[4];
            #pragma unroll
            for (int pt = 0; pt < 4; ++pt) {
                const int brow = 16 * pt + l15;
                bf[pt] = *(const short8*)(gbB + brow * 128 + (cb ^ srowswz(brow)));
            }
            #pragma unroll
            for (int ct = 0; ct < 4; ++ct) {
                const int c = 64 * ww + 16 * ct + l15;
                short8 af;
                #pragma unroll
                for (int j = 0; j < 8; ++j) {
                    const int q2 = 32 * kc + 8 * lh + j;
                    af[j] = *(const short*)(sAb + q2 * 512 + ((2 * c) ^ srowswz(q2)));
                }
                #pragma unroll
                for (int pt = 0; pt < 4; ++pt)
                    eacc[ct][pt] = __builtin_amdgcn_mfma_f32_16x16x32_bf16(af, bf[pt], eacc[ct][pt], 0, 0, 0);
            }
        }

        // Epilogue: lane = token p (28B segments; quad patches complete 112B
        // runs on the same CU -> L2 merge). xv from sA (bf16).
        #pragma unroll
        for (int pt = 0; pt < 4; ++pt) {
            const int p = 16 * pt + l15;
            if (p > 48) continue;
            const int i = p / 7, j = p - 7 * (p / 7);
            const size_t base = xpatch + (size_t)i * W_ + j;
            #pragma unroll
            for (int ct = 0; ct < 4; ++ct) {
                #pragma unroll
                for (int r = 0; r < 4; ++r) {
                    const int c = 64 * ww + 16 * ct + 4 * lh + r;
                    const size_t g = base + (size_t)c * HW_;
                    const float ec = eacc[ct][pt][r];
                    const float xv = __bfloat162float(
                        *(const __hip_bfloat16*)(sAb + p * 512 + ((2 * c) ^ srowswz(p))));
                    out_ec [g] = ec;
                    out_img[g] = xv * fmaf(beta, ec, xv);
                }
            }
        }
    }
}

extern "C" void kernel_launch(void* const* d_in, const int* in_sizes, int n_in,
                              void* d_out, int out_size, void* d_ws, size_t ws_size,
                              hipStream_t stream) {
    const float* x    = (const float*)d_in[0];
    const float* beta = (const float*)d_in[1];
    float* out = (float*)d_out;
    psa_kernel<<<dim3(M_), dim3(1024), 0, stream>>>(
        x, beta,
        out,
        out + OFF_SC,
        out + OFF_COV,
        out + OFF_L,
        out + OFF_EC);
}

// Round 7
// 339.577 us; speedup vs baseline: 1.6243x; 1.6243x over previous
//
#include <hip/hip_runtime.h>
#include <hip/hip_bf16.h>
#include <cstdint>
#include <cstddef>

constexpr int C_  = 256;
constexpr int H_  = 224;
constexpr int W_  = 224;
constexpr int P_  = 49;
constexpr int M_  = 1024;
constexpr int HW_ = H_ * W_;

constexpr size_t IMG_ELEMS = (size_t)4 * C_ * H_ * W_;
constexpr size_t SCO_ELEMS = (size_t)4 * M_ * P_ * P_;
constexpr size_t OFF_SC  = IMG_ELEMS;
constexpr size_t OFF_COV = OFF_SC  + SCO_ELEMS;
constexpr size_t OFF_L   = OFF_COV + SCO_ELEMS;
constexpr size_t OFF_EC  = OFF_L   + SCO_ELEMS;

typedef __attribute__((ext_vector_type(8))) short short8;
typedef __attribute__((ext_vector_type(4))) float f32x4;

// Workspace: patch-major bf16 staging, 64 p-slots per (bm,c) row (128B rows).
//   ws_ec : [4096][256][64] bf16   (134,217,728 B)
//   ws_out: same size, offset WS_HALF
constexpr size_t WS_ROW   = 64;
constexpr size_t WS_PATCH = (size_t)C_ * WS_ROW;            // 16384 elems
constexpr size_t WS_HALF  = (size_t)4096 * WS_PATCH * 2;    // bytes per array
constexpr size_t WS_NEED  = 2 * WS_HALF;                    // 268,435,456 B

// LDS byte map (compute kernel, 48,240 -> 3 blocks/CU):
//   sA  : [0, 25088)        49 rows x 512B  bf16 A row-major, XOR-swizzled rows
//   Gb  : [25088, 31360)    49 rows x 128B  bf16 (G - u); Lb overlays after cov
//   Scb : [31360, 37632)    49 rows x 128B  bf16 Sc
//   sG  : [37632, 47432)    49 x 50 f32     G -> exp -> Sc (in place)
//   rowmax/u/w/T2 : 4 x 49 f32
// Out-of-range MFMA fragment reads (rows/q 49..63) all end in discarded D
// rows/cols or multiply Lb's zero k-columns; regions read are finite bf16.
constexpr int SA_OFF  = 0;
constexpr int GB_OFF  = 25088;
constexpr int SCB_OFF = 31360;
constexpr int SG_OFF  = 37632;
constexpr int RM_OFF  = 47432;
constexpr int U_OFF   = 47632;
constexpr int W_OFF   = 47832;
constexpr int T2_OFF  = 48032;
constexpr int SMEM_BYTES = 48240;

__device__ __forceinline__ int srowswz(int r) { return ((r ^ (r >> 3)) & 7) << 4; }

template<bool SPLIT>
__global__ __launch_bounds__(256, 3)
void psa_kernel(const float* __restrict__ x, const float* __restrict__ betap,
                float* __restrict__ out_img, float* __restrict__ out_sc,
                float* __restrict__ out_cov, float* __restrict__ out_l,
                float* __restrict__ out_ec,
                __hip_bfloat16* __restrict__ ws_ec,
                __hip_bfloat16* __restrict__ ws_out)
{
    __shared__ __align__(16) unsigned char smem[SMEM_BYTES];
    float* sG     = (float*)(smem + SG_OFF);
    float* rowmax = (float*)(smem + RM_OFF);
    float* uArr   = (float*)(smem + U_OFF);
    float* wArr   = (float*)(smem + W_OFF);
    float* t2Arr  = (float*)(smem + T2_OFF);

    const int tid = threadIdx.x;
    const int bid = blockIdx.x;
    const int bm  = ((bid & 7) << 9) | (bid >> 3);   // XCD-bijective swizzle
    const int b   = bm >> 10;
    const int m   = bm & (M_ - 1);
    const int mh  = m >> 5;
    const int mw  = m & 31;
    const float beta = betap[0];
    const size_t xpatch = (((size_t)b * C_ * H_) + (size_t)mh * 7) * W_ + (size_t)mw * 7;

    const int wid = tid >> 6, lane = tid & 63, l15 = lane & 15, lh = lane >> 4;

    // ---- Phase 0: stage x -> sA (bf16, swizzled). thread = channel ----
    {
        const int c = tid;
        const float* src = x + xpatch + (size_t)c * HW_;
        #pragma unroll
        for (int i = 0; i < 7; ++i) {
            #pragma unroll
            for (int j = 0; j < 7; ++j) {
                const int p = i * 7 + j;
                *(__hip_bfloat16*)(smem + SA_OFF + p * 512 + ((2 * c) ^ srowswz(p))) =
                    __float2bfloat16(src[i * W_ + j]);
            }
        }
    }
    __syncthreads();

    // ---- Phase 1: G = A A^T (MFMA, K=256). wave wid -> rows 16wid..+15 ----
    {
        f32x4 acc[4] = {f32x4{0,0,0,0}, f32x4{0,0,0,0}, f32x4{0,0,0,0}, f32x4{0,0,0,0}};
        const int arow = 16 * wid + l15;
        #pragma unroll
        for (int kc = 0; kc < 8; ++kc) {
            const int cb = 64 * kc + 16 * lh;
            const short8 af = *(const short8*)(smem + SA_OFF + arow * 512 + (cb ^ srowswz(arow)));
            #pragma unroll
            for (int t = 0; t < 4; ++t) {
                const int brow = 16 * t + l15;
                const short8 bf = *(const short8*)(smem + SA_OFF + brow * 512 + (cb ^ srowswz(brow)));
                acc[t] = __builtin_amdgcn_mfma_f32_16x16x32_bf16(af, bf, acc[t], 0, 0, 0);
            }
        }
        #pragma unroll
        for (int t = 0; t < 4; ++t) {
            const int q = 16 * t + l15;
            if (q <= 48) {
                #pragma unroll
                for (int r = 0; r < 4; ++r) {
                    const int p = 16 * wid + 4 * lh + r;
                    if (p <= 48) sG[p * 50 + q] = acc[t][r];
                }
            }
        }
    }
    __syncthreads();

    // ---- Phase 2: rowmax + u (= rowmean; G symmetric). 4 lanes/row ----
    if (tid < 196) {
        const int row = tid >> 2, s = tid & 3;
        const int qa = s * 13, qb = (qa + 13 < 49) ? qa + 13 : 49;
        float mx = -3.4e38f, sm = 0.f;
        for (int q = qa; q < qb; ++q) {
            const float v = sG[row * 50 + q];
            mx = fmaxf(mx, v); sm += v;
        }
        mx = fmaxf(mx, __shfl_xor(mx, 1));
        mx = fmaxf(mx, __shfl_xor(mx, 2));
        sm += __shfl_xor(sm, 1);
        sm += __shfl_xor(sm, 2);
        if (s == 0) { rowmax[row] = mx; uArr[row] = sm * (1.f / 49.f); }
    }
    __syncthreads();

    // ---- Phase 3: fused Gb = bf16(G - u) + in-place exp; zero pad cols ----
    for (int e = tid; e < 49 * 64; e += 256) {
        const int p = e >> 6, r = e & 63;
        if (r < 49) {
            const float gv = sG[p * 50 + r];
            *(__hip_bfloat16*)(smem + GB_OFF + p * 128 + ((2 * r) ^ srowswz(p))) =
                __float2bfloat16(gv - uArr[r]);
            sG[p * 50 + r] = __expf(gv - rowmax[p]);
        } else {
            *(short*)(smem + GB_OFF  + p * 128 + ((2 * r) ^ srowswz(p))) = 0;
            *(short*)(smem + SCB_OFF + p * 128 + ((2 * r) ^ srowswz(p))) = 0;
        }
    }
    __syncthreads();

    // ---- Phase 4: rowsum -> scale; write Sc (fp32 LDS + global + bf16 Scb) ----
    if (tid < 196) {
        const int row = tid >> 2, s = tid & 3;
        const int qa = s * 13, qb = (qa + 13 < 49) ? qa + 13 : 49;
        float sm = 0.f;
        for (int q = qa; q < qb; ++q) sm += sG[row * 50 + q];
        sm += __shfl_xor(sm, 1);
        sm += __shfl_xor(sm, 2);
        const float rinv = 1.f / sm;
        float* sc_g = out_sc + (size_t)bm * (P_ * P_) + row * 49;
        for (int q = qa; q < qb; ++q) {
            const float v = sG[row * 50 + q] * rinv;
            sG[row * 50 + q] = v;
            sc_g[q] = v;
            *(__hip_bfloat16*)(smem + SCB_OFF + row * 128 + ((2 * q) ^ srowswz(row))) =
                __float2bfloat16(v);
        }
    }
    __syncthreads();

    // ---- Phase 5a: w = colmean(Sc) ----
    if (tid < 196) {
        const int r = tid >> 2, s = tid & 3;
        const int pa = s * 13, pb = (pa + 13 < 49) ? pa + 13 : 49;
        float sm = 0.f;
        for (int p = pa; p < pb; ++p) sm += sG[p * 50 + r];
        sm += __shfl_xor(sm, 1);
        sm += __shfl_xor(sm, 2);
        if (s == 0) wArr[r] = sm * (1.f / 49.f);
    }
    __syncthreads();

    // ---- Phase 5b: T2[p] = sum_r Gb[p][r] * w[r] ----
    if (tid < 196) {
        const int p = tid >> 2, s = tid & 3;
        const int ra = s * 13, rb = (ra + 13 < 49) ? ra + 13 : 49;
        float sm = 0.f;
        for (int r = ra; r < rb; ++r) {
            const float gb = __bfloat162float(
                *(const __hip_bfloat16*)(smem + GB_OFF + p * 128 + ((2 * r) ^ srowswz(p))));
            sm += gb * wArr[r];
        }
        sm += __shfl_xor(sm, 1);
        sm += __shfl_xor(sm, 2);
        if (s == 0) t2Arr[p] = sm;
    }
    __syncthreads();

    // ---- Phase 6: cov MFMA: D = Gb . Scb^T (K=64) ----
    f32x4 cacc[4] = {f32x4{0,0,0,0}, f32x4{0,0,0,0}, f32x4{0,0,0,0}, f32x4{0,0,0,0}};
    {
        const int arow = 16 * wid + l15;
        #pragma unroll
        for (int kc = 0; kc < 2; ++kc) {
            const int cb = 64 * kc + 16 * lh;
            const short8 af = *(const short8*)(smem + GB_OFF + arow * 128 + (cb ^ srowswz(arow)));
            #pragma unroll
            for (int t = 0; t < 4; ++t) {
                const int brow = 16 * t + l15;
                const short8 bf = *(const short8*)(smem + SCB_OFF + brow * 128 + (cb ^ srowswz(brow)));
                cacc[t] = __builtin_amdgcn_mfma_f32_16x16x32_bf16(af, bf, cacc[t], 0, 0, 0);
            }
        }
    }
    __syncthreads();   // cov reads done before Lb overlays Gb

    // ---- Phase 7: cv = (cacc - T2[p])/49; L = Sc + cv; write cov/L/Lb ----
    {
        float* cov_g = out_cov + (size_t)bm * (P_ * P_);
        float* l_g   = out_l   + (size_t)bm * (P_ * P_);
        #pragma unroll
        for (int t = 0; t < 4; ++t) {
            const int q = 16 * t + l15;
            #pragma unroll
            for (int r = 0; r < 4; ++r) {
                const int p = 16 * wid + 4 * lh + r;
                if (p <= 48 && q <= 48) {
                    const float cv = (cacc[t][r] - t2Arr[p]) * (1.f / 49.f);
                    const float lv = sG[p * 50 + q] + cv;
                    cov_g[p * 49 + q] = cv;
                    l_g  [p * 49 + q] = lv;
                    *(__hip_bfloat16*)(smem + GB_OFF + p * 128 + ((2 * q) ^ srowswz(p))) =
                        __float2bfloat16(lv);   // Lb; cols 49..63 keep zeros
                }
            }
        }
    }
    __syncthreads();

    // ---- Phase 8: Ec^T = A^T . L^T (D[c][p]); wave wid -> c in [64wid, +64) ----
    {
        f32x4 acc[4][4];   // [ct][pt]
        #pragma unroll
        for (int i = 0; i < 4; ++i)
            #pragma unroll
            for (int j2 = 0; j2 < 4; ++j2) acc[i][j2] = f32x4{0, 0, 0, 0};

        #pragma unroll
        for (int kc = 0; kc < 2; ++kc) {
            const int cb = 64 * kc + 16 * lh;
            short8 bf[4];
            #pragma unroll
            for (int pt = 0; pt < 4; ++pt) {
                const int brow = 16 * pt + l15;
                bf[pt] = *(const short8*)(smem + GB_OFF + brow * 128 + (cb ^ srowswz(brow)));
            }
            #pragma unroll
            for (int ct = 0; ct < 4; ++ct) {
                const int c = 64 * wid + 16 * ct + l15;
                short8 af;
                #pragma unroll
                for (int j = 0; j < 8; ++j) {
                    const int q2 = 32 * kc + 8 * lh + j;
                    af[j] = *(const short*)(smem + SA_OFF + q2 * 512 + ((2 * c) ^ srowswz(q2)));
                }
                #pragma unroll
                for (int pt = 0; pt < 4; ++pt)
                    acc[ct][pt] = __builtin_amdgcn_mfma_f32_16x16x32_bf16(af, bf[pt], acc[ct][pt], 0, 0, 0);
            }
        }

        if (SPLIT) {
            // Patch-major bf16 staging: ws[(bm*256+c)*64 + p]. Per store instr:
            // 16 lanes = consecutive p -> 32B segments; no partial-line waste.
            // p in 49..63 stores deterministic garbage (fold ignores those slots;
            // sA reads land in Gb/Scb region, finite bf16).
            __hip_bfloat16* wec = ws_ec  + (size_t)bm * WS_PATCH;
            __hip_bfloat16* wou = ws_out + (size_t)bm * WS_PATCH;
            #pragma unroll
            for (int pt = 0; pt < 4; ++pt) {
                const int p = 16 * pt + l15;
                #pragma unroll
                for (int ct = 0; ct < 4; ++ct) {
                    #pragma unroll
                    for (int r = 0; r < 4; ++r) {
                        const int c = 64 * wid + 16 * ct + 4 * lh + r;
                        const float ec = acc[ct][pt][r];
                        const float xv = __bfloat162float(
                            *(const __hip_bfloat16*)(smem + SA_OFF + p * 512 + ((2 * c) ^ srowswz(p))));
                        wec[(size_t)c * WS_ROW + p] = __float2bfloat16(ec);
                        wou[(size_t)c * WS_ROW + p] = __float2bfloat16(xv * fmaf(beta, ec, xv));
                    }
                }
            }
        } else {
            // Fallback: direct scatter stores (R5 behavior)
            #pragma unroll
            for (int pt = 0; pt < 4; ++pt) {
                const int p = 16 * pt + l15;
                if (p > 48) continue;
                const int i = p / 7, j = p - 7 * (p / 7);
                const size_t base = xpatch + (size_t)i * W_ + j;
                #pragma unroll
                for (int ct = 0; ct < 4; ++ct) {
                    #pragma unroll
                    for (int r = 0; r < 4; ++r) {
                        const int c = 64 * wid + 16 * ct + 4 * lh + r;
                        const size_t g = base + (size_t)c * HW_;
                        const float ec = acc[ct][pt][r];
                        const float xv = __bfloat162float(
                            *(const __hip_bfloat16*)(smem + SA_OFF + p * 512 + ((2 * c) ^ srowswz(p))));
                        out_ec [g] = ec;
                        out_img[g] = xv * fmaf(beta, ec, xv);
                    }
                }
            }
        }
    }
}

// Fold: one block per (b,c,mh) strip. Stage 32 patches' (c,:) rows from ws
// into LDS, emit out_img/out_ec as full-line coalesced float4 stores.
__global__ __launch_bounds__(256)
void fold_kernel(const __hip_bfloat16* __restrict__ ws_ec,
                 const __hip_bfloat16* __restrict__ ws_out,
                 float* __restrict__ out_img, float* __restrict__ out_ec)
{
    __shared__ __hip_bfloat16 lec[32][64];
    __shared__ __hip_bfloat16 lou[32][64];

    const int bid = blockIdx.x;
    const int bc  = bid >> 5;         // b*256 + c
    const int mh  = bid & 31;
    const int b   = bc >> 8;
    const int c   = bc & 255;
    const int t   = threadIdx.x;

    // Stage: 32 rows x 56 slots (7 x short8); slots 49..55 unused garbage.
    if (t < 224) {
        const int k = t / 7, o = (t - k * 7) * 8;
        const size_t base = (((size_t)(b << 10) + (mh << 5) + k) * C_ + c) * WS_ROW + o;
        *(short8*)&lec[k][o] = *(const short8*)&ws_ec [base];
        *(short8*)&lou[k][o] = *(const short8*)&ws_out[base];
    }
    __syncthreads();

    const size_t rowbase = ((size_t)bc * H_ + (size_t)mh * 7) * W_;
    for (int idx = t; idx < 392; idx += 256) {
        const int i  = idx / 56;
        const int w0 = (idx - i * 56) * 4;
        float4 vo, ve;
        #pragma unroll
        for (int e = 0; e < 4; ++e) {
            const int w  = w0 + e;
            const int mw = w / 7;
            const int p  = i * 7 + (w - mw * 7);
            ((float*)&ve)[e] = __bfloat162float(lec[mw][p]);
            ((float*)&vo)[e] = __bfloat162float(lou[mw][p]);
        }
        *(float4*)&out_ec [rowbase + (size_t)i * W_ + w0] = ve;
        *(float4*)&out_img[rowbase + (size_t)i * W_ + w0] = vo;
    }
}

extern "C" void kernel_launch(void* const* d_in, const int* in_sizes, int n_in,
                              void* d_out, int out_size, void* d_ws, size_t ws_size,
                              hipStream_t stream) {
    const float* x    = (const float*)d_in[0];
    const float* beta = (const float*)d_in[1];
    float* out = (float*)d_out;

    if (ws_size >= WS_NEED) {
        __hip_bfloat16* ws_ec  = (__hip_bfloat16*)d_ws;
        __hip_bfloat16* ws_out = (__hip_bfloat16*)((unsigned char*)d_ws + WS_HALF);
        psa_kernel<true><<<dim3(4 * M_), dim3(256), 0, stream>>>(
            x, beta, out, out + OFF_SC, out + OFF_COV, out + OFF_L, out + OFF_EC,
            ws_ec, ws_out);
        fold_kernel<<<dim3(1024 * 32), dim3(256), 0, stream>>>(
            ws_ec, ws_out, out, out + OFF_EC);
    } else {
        psa_kernel<false><<<dim3(4 * M_), dim3(256), 0, stream>>>(
            x, beta, out, out + OFF_SC, out + OFF_COV, out + OFF_L, out + OFF_EC,
            nullptr, nullptr);
    }
}